// Round 17
// baseline (104.693 us; speedup 1.0000x reference)
//
#include <hip/hip_runtime.h>
#include <hip/hip_bf16.h>

typedef unsigned short u16;
typedef __attribute__((ext_vector_type(8))) short short8;
typedef __attribute__((ext_vector_type(4))) float floatx4;

#define NROWS 8192
#define DIM 256

__device__ __forceinline__ void atomicMinFloat(float* addr, float val) {
    if (val >= 0.0f) {
        atomicMin((int*)addr, __float_as_int(val));
    } else {
        atomicMax((unsigned int*)addr, __float_as_uint(val));
    }
}

__device__ __forceinline__ u16 f32_to_bf16_rne(float x) {
    unsigned int u = __float_as_uint(x);
    unsigned int r = (u + 0x7fffu + ((u >> 16) & 1u)) >> 16;
    return (u16)r;
}

// C(M) = -logp * exp(logp); quasiconcave in M => rowmin = min(C(minM), C(maxM)).
__device__ __forceinline__ float c_of_m(float m) {
    const float INV_SIG = 1.0f / 0.3f;
    const float KC = 0.28503427f;  // -ln(0.3) - 0.5*ln(2*pi)
    float z = (m - 1.0f) * INV_SIG;
    float logp = fmaf(-0.5f * z, z, KC);
    return -logp * __expf(logp);
}

// Normalize rows (L2-norm clamped at 1e-8), wave per row, float4 loads.
// BOTH X and Y are written in MFMA fragment ("panel") layout:
//   element (row r, k) -> flat[ ((p*8+kt)*64 + lq*16 + lm)*8 + j ]
//   p=r>>4, lm=r&15, kt=k>>5, lq=(k>>3)&3, j=k&7.
// A fragment load is then base + lane*16B: one coalesced dwordx4.
// Verified end-to-end R5/R11/R14/R15/R16 (absmax 1.5e-5).
__global__ __launch_bounds__(256) void normalize_kernel(const float* __restrict__ Ex,
                                                        const float* __restrict__ Ey,
                                                        u16* __restrict__ Xs,
                                                        u16* __restrict__ Ys,
                                                        float* __restrict__ out) {
    const int t = threadIdx.x;
    const int ln = t & 63;
    const int row = blockIdx.x * 4 + (t >> 6);
    const float* src = (blockIdx.y == 0) ? Ex : Ey;
    u16* dst = (blockIdx.y == 0) ? Xs : Ys;

    float4 v = *(const float4*)(src + (size_t)row * DIM + ln * 4);
    float s = fmaf(v.x, v.x, fmaf(v.y, v.y, fmaf(v.z, v.z, v.w * v.w)));
    #pragma unroll
    for (int m = 32; m >= 1; m >>= 1) s += __shfl_xor(s, m, 64);
    float inv = 1.0f / fmaxf(sqrtf(s), 1e-8f);

    ushort4 o;
    o.x = f32_to_bf16_rne(v.x * inv);
    o.y = f32_to_bf16_rne(v.y * inv);
    o.z = f32_to_bf16_rne(v.z * inv);
    o.w = f32_to_bf16_rne(v.w * inv);

    const int p = row >> 4;
    const int lm = row & 15;
    const int kt = ln >> 3;
    const int lq = (ln >> 1) & 3;
    const int j4 = (ln & 1) * 4;
    const size_t off = ((size_t)((p * 8 + kt) * 64 + lq * 16 + lm)) * 8 + j4;
    *(ushort4*)(dst + off) = o;

    if (blockIdx.y == 0 && ln == 0) out[row] = __uint_as_float(0x7f800000u);  // +inf
}

// Block = 512 rows x 512 cols, 512 threads = 8 waves, each wave a distinct
// 64-row group (zero A duplication); all waves share each 64-col B tile.
// R17 change vs R16: B staging transport switched from global_load_lds DMA
// (measured ~10 B/cyc/CU service -- the plateau-fitting constant across
// R2/R6/R11/R14/R15) to global_load_dwordx4 -> VGPR -> ds_write_b128
// (L2 ~56 B/cyc/CU + LDS-write pipe). Loads/writes run in 2-unit batches
// interleaved with compute halves (transient VGPR <= 16; avoids the
// R8-style allocator collapse near the 256-reg cap). __syncthreads'
// lgkmcnt(0) drain orders writes before the next ct's reads.
// Staged traffic stays 0.5 MB/CU. Grid 256 (1 block/CU):
// b&15 = row-tile, b>>4 = col-group.
__global__ void __launch_bounds__(512, 2)
gemm_min_kernel(const u16* __restrict__ Xs,
                const u16* __restrict__ Ys,
                float* __restrict__ out) {
    __shared__ u16 Bs[2][32 * 512];  // 2 x 32 KB

    const int tid = threadIdx.x;
    const int w = tid >> 6;      // 0..7 row-group
    const int lane = tid & 63;
    const int lq = lane >> 4;
    const int lm = lane & 15;

    const int b = blockIdx.x;
    const int rowStart = (b & 15) * 512;
    const int rowPan0 = (b & 15) * 32 + w * 4;
    const u16* ybase = Ys + (size_t)((b >> 4) * 32) * 4096;  // advances 16384/ct

    // B tile = 32 x 1 KB units; unit u -> (panel u>>3, kt u&7), LDS slot
    // u*512 so fragment reads are Bs[(cg*8+kt)*512 + lane*8] (conflict-free).
    // Wave w owns units w*4 .. w*4+3, moved in 2-unit register batches.
    auto loadB2 = [&](uint4 (&r)[2], const u16* yb, int i0) {
        #pragma unroll
        for (int i = 0; i < 2; ++i) {
            const int u = w * 4 + i0 + i;
            r[i] = *(const uint4*)(yb + (u >> 3) * 4096 + (u & 7) * 512 + lane * 8);
        }
    };
    auto writeB2 = [&](int buf, const uint4 (&r)[2], int i0) {
        #pragma unroll
        for (int i = 0; i < 2; ++i) {
            const int u = w * 4 + i0 + i;
            *(uint4*)(&Bs[buf][u * 512 + lane * 8]) = r[i];
        }
    };

    short8 a[4][8];
    auto loadA = [&](int kt) {
        #pragma unroll
        for (int rg = 0; rg < 4; ++rg)
            a[rg][kt] = *(const short8*)(
                Xs + ((size_t)(rowPan0 + rg) * 8 + kt) * 512 + lane * 8);
    };

    floatx4 mn4[4], mx4[4];
    #pragma unroll
    for (int rg = 0; rg < 4; ++rg) {
        mn4[rg] = (floatx4){3.4e38f, 3.4e38f, 3.4e38f, 3.4e38f};
        mx4[rg] = (floatx4){-3.4e38f, -3.4e38f, -3.4e38f, -3.4e38f};
    }

    floatx4 acc[4][4];
    auto zeroAcc = [&]() {
        #pragma unroll
        for (int i = 0; i < 4; ++i)
            #pragma unroll
            for (int j = 0; j < 4; ++j)
                acc[i][j] = (floatx4){0.0f, 0.0f, 0.0f, 0.0f};
    };
    // kt = h*4 .. h*4+3 of the K loop on buffer `buf`.
    auto computeHalf = [&](int buf, int h) {
        #pragma unroll
        for (int k = 0; k < 4; ++k) {
            const int kt = h * 4 + k;
            short8 bf[4];
            #pragma unroll
            for (int cg = 0; cg < 4; ++cg)
                bf[cg] = *(const short8*)(&Bs[buf][(cg * 8 + kt) * 512 + lane * 8]);
            #pragma unroll
            for (int cg = 0; cg < 4; ++cg)
                #pragma unroll
                for (int rg = 0; rg < 4; ++rg)
                    acc[rg][cg] = __builtin_amdgcn_mfma_f32_16x16x32_bf16(
                        a[rg][kt], bf[cg], acc[rg][cg], 0, 0, 0);
        }
    };
    auto fold = [&]() {
        #pragma unroll
        for (int rg = 0; rg < 4; ++rg)
            #pragma unroll
            for (int cg = 0; cg < 4; ++cg)
                #pragma unroll
                for (int r = 0; r < 4; ++r) {
                    float m = acc[rg][cg][r];
                    mn4[rg][r] = fminf(mn4[rg][r], m);
                    mx4[rg][r] = fmaxf(mx4[rg][r], m);
                }
    };

    // --- ct = 0, peeled: overlap A prologue + B0/B1 staging with compute ---
    {
        uint4 ra[2], rc[2];
        loadB2(ra, ybase, 0);
        loadB2(rc, ybase, 2);
        loadA(0);
        loadA(1);
        writeB2(0, ra, 0);
        writeB2(0, rc, 2);
        __syncthreads();  // lgkmcnt(0): B0 writes visible; vmcnt drains A k0/k1

        loadB2(ra, ybase + 16384, 0);  // ct=1 prefetch, batch 0
        loadA(2); loadA(3); loadA(4); loadA(5); loadA(6); loadA(7);
        zeroAcc();
        computeHalf(0, 0);
        writeB2(1, ra, 0);
        loadB2(rc, ybase + 16384, 2);  // ct=1 prefetch, batch 1
        computeHalf(0, 1);
        writeB2(1, rc, 2);
        fold();
        ybase += 16384;
    }

    // --- cts 1..7: steady state ---
    #pragma unroll 1
    for (int ct = 1; ct < 8; ++ct) {
        const int buf = ct & 1;
        zeroAcc();
        __syncthreads();  // lgkmcnt(0): ct's B writes visible to all waves
        if (ct < 7) {
            uint4 ra[2], rc[2];
            loadB2(ra, ybase + 16384, 0);
            computeHalf(buf, 0);
            writeB2(buf ^ 1, ra, 0);
            loadB2(rc, ybase + 16384, 2);
            computeHalf(buf, 1);
            writeB2(buf ^ 1, rc, 2);
        } else {
            computeHalf(buf, 0);
            computeHalf(buf, 1);
        }
        fold();
        ybase += 16384;  // loop-carried: blocks cross-ct hoisting
    }

    // Single epilogue: quad-lane reduce, eval C twice (quasiconcavity),
    // fire-and-forget atomicMin (no read guard -- R3 post-mortem).
    #pragma unroll
    for (int rg = 0; rg < 4; ++rg) {
        #pragma unroll
        for (int r = 0; r < 4; ++r) {
            float mn = mn4[rg][r];
            float mx = mx4[rg][r];
            #pragma unroll
            for (int mofs = 1; mofs < 16; mofs <<= 1) {
                mn = fminf(mn, __shfl_xor(mn, mofs, 64));
                mx = fmaxf(mx, __shfl_xor(mx, mofs, 64));
            }
            if (lm == 0) {
                float cmin = fminf(c_of_m(mn), c_of_m(mx));
                int row = rowStart + w * 64 + rg * 16 + lq * 4 + r;
                atomicMinFloat(&out[row], cmin);
            }
        }
    }
}

extern "C" void kernel_launch(void* const* d_in, const int* in_sizes, int n_in,
                              void* d_out, int out_size, void* d_ws, size_t ws_size,
                              hipStream_t stream) {
    const float* Ex = (const float*)d_in[0];
    const float* Ey = (const float*)d_in[1];
    float* out = (float*)d_out;
    u16* Xs = (u16*)d_ws;                // 4 MB, panel layout
    u16* Ys = Xs + (size_t)NROWS * DIM;  // 4 MB, panel layout

    hipLaunchKernelGGL(normalize_kernel, dim3(NROWS / 4, 2), dim3(256), 0, stream,
                       Ex, Ey, Xs, Ys, out);
    hipLaunchKernelGGL(gemm_min_kernel, dim3(16 * 16), dim3(512), 0, stream,
                       Xs, Ys, out);
}

// Round 18
// 95.266 us; speedup vs baseline: 1.0990x; 1.0990x over previous
//
#include <hip/hip_runtime.h>
#include <hip/hip_bf16.h>

typedef unsigned short u16;
typedef __attribute__((ext_vector_type(8))) short short8;
typedef __attribute__((ext_vector_type(4))) float floatx4;

#define NROWS 8192
#define DIM 256

__device__ __forceinline__ void atomicMinFloat(float* addr, float val) {
    if (val >= 0.0f) {
        atomicMin((int*)addr, __float_as_int(val));
    } else {
        atomicMax((unsigned int*)addr, __float_as_uint(val));
    }
}

__device__ __forceinline__ u16 f32_to_bf16_rne(float x) {
    unsigned int u = __float_as_uint(x);
    unsigned int r = (u + 0x7fffu + ((u >> 16) & 1u)) >> 16;
    return (u16)r;
}

// C(M) = -logp * exp(logp); quasiconcave in M => rowmin = min(C(minM), C(maxM)).
__device__ __forceinline__ float c_of_m(float m) {
    const float INV_SIG = 1.0f / 0.3f;
    const float KC = 0.28503427f;  // -ln(0.3) - 0.5*ln(2*pi)
    float z = (m - 1.0f) * INV_SIG;
    float logp = fmaf(-0.5f * z, z, KC);
    return -logp * __expf(logp);
}

// Normalize rows (L2-norm clamped at 1e-8), wave per row, float4 loads.
// BOTH X and Y are written in MFMA fragment ("panel") layout:
//   element (row r, k) -> flat[ ((p*8+kt)*64 + lq*16 + lm)*8 + j ]
//   p=r>>4, lm=r&15, kt=k>>5, lq=(k>>3)&3, j=k&7.
// A fragment load is then base + lane*16B: one coalesced dwordx4.
// Verified end-to-end R5/R11/R14/R15/R16 (absmax 1.5e-5).
__global__ __launch_bounds__(256) void normalize_kernel(const float* __restrict__ Ex,
                                                        const float* __restrict__ Ey,
                                                        u16* __restrict__ Xs,
                                                        u16* __restrict__ Ys,
                                                        float* __restrict__ out) {
    const int t = threadIdx.x;
    const int ln = t & 63;
    const int row = blockIdx.x * 4 + (t >> 6);
    const float* src = (blockIdx.y == 0) ? Ex : Ey;
    u16* dst = (blockIdx.y == 0) ? Xs : Ys;

    float4 v = *(const float4*)(src + (size_t)row * DIM + ln * 4);
    float s = fmaf(v.x, v.x, fmaf(v.y, v.y, fmaf(v.z, v.z, v.w * v.w)));
    #pragma unroll
    for (int m = 32; m >= 1; m >>= 1) s += __shfl_xor(s, m, 64);
    float inv = 1.0f / fmaxf(sqrtf(s), 1e-8f);

    ushort4 o;
    o.x = f32_to_bf16_rne(v.x * inv);
    o.y = f32_to_bf16_rne(v.y * inv);
    o.z = f32_to_bf16_rne(v.z * inv);
    o.w = f32_to_bf16_rne(v.w * inv);

    const int p = row >> 4;
    const int lm = row & 15;
    const int kt = ln >> 3;
    const int lq = (ln >> 1) & 3;
    const int j4 = (ln & 1) * 4;
    const size_t off = ((size_t)((p * 8 + kt) * 64 + lq * 16 + lm)) * 8 + j4;
    *(ushort4*)(dst + off) = o;

    if (blockIdx.y == 0 && ln == 0) out[row] = __uint_as_float(0x7f800000u);  // +inf
}

// Block = 512 rows x 512 cols, 512 threads = 8 waves, each wave a distinct
// 64-row group (zero A duplication); all waves share each 64-col B tile.
// R18 change vs R16: B staging transport = global_load_dwordx4 -> VGPR ->
// ds_write_b128 executed as one immediate sequence (transient 16 VGPRs,
// NOTHING held across compute -- R17 held batches across compute halves and
// spilled 25 MB). Tests the DMA-service theory cleanly: global_load_lds was
// the common instrument at every ~10 B/cyc/CU plateau point (R2/R6/R11/
// R14/R15); classic transport should run at L2 rate (~56 B/cyc/CU).
// Exposed cost ~600 cyc/ct before compute; ~2 us total.
// Staged traffic stays 0.5 MB/CU. Grid 256 (1 block/CU):
// b&15 = row-tile, b>>4 = col-group.
__global__ void __launch_bounds__(512, 2)
gemm_min_kernel(const u16* __restrict__ Xs,
                const u16* __restrict__ Ys,
                float* __restrict__ out) {
    __shared__ u16 Bs[2][32 * 512];  // 2 x 32 KB

    const int tid = threadIdx.x;
    const int w = tid >> 6;      // 0..7 row-group
    const int lane = tid & 63;
    const int lq = lane >> 4;
    const int lm = lane & 15;

    const int b = blockIdx.x;
    const int rowStart = (b & 15) * 512;
    const int rowPan0 = (b & 15) * 32 + w * 4;
    const u16* ybase = Ys + (size_t)((b >> 4) * 32) * 4096;  // advances 16384/ct

    // B tile = 32 x 1 KB units; unit u -> (panel u>>3, kt u&7), LDS slot
    // u*512 so fragment reads are Bs[(cg*8+kt)*512 + lane*8] (conflict-free).
    // Wave w owns units w*4..w*4+3. Immediate load->write, no held state.
    auto stageB = [&](int buf, const u16* yb) {
        uint4 r[4];
        #pragma unroll
        for (int i = 0; i < 4; ++i) {
            const int u = w * 4 + i;
            r[i] = *(const uint4*)(yb + (u >> 3) * 4096 + (u & 7) * 512 + lane * 8);
        }
        #pragma unroll
        for (int i = 0; i < 4; ++i) {
            const int u = w * 4 + i;
            *(uint4*)(&Bs[buf][u * 512 + lane * 8]) = r[i];
        }
    };

    short8 a[4][8];
    auto loadA = [&](int kt) {
        #pragma unroll
        for (int rg = 0; rg < 4; ++rg)
            a[rg][kt] = *(const short8*)(
                Xs + ((size_t)(rowPan0 + rg) * 8 + kt) * 512 + lane * 8);
    };

    floatx4 mn4[4], mx4[4];
    #pragma unroll
    for (int rg = 0; rg < 4; ++rg) {
        mn4[rg] = (floatx4){3.4e38f, 3.4e38f, 3.4e38f, 3.4e38f};
        mx4[rg] = (floatx4){-3.4e38f, -3.4e38f, -3.4e38f, -3.4e38f};
    }

    floatx4 acc[4][4];
    auto zeroAcc = [&]() {
        #pragma unroll
        for (int i = 0; i < 4; ++i)
            #pragma unroll
            for (int j = 0; j < 4; ++j)
                acc[i][j] = (floatx4){0.0f, 0.0f, 0.0f, 0.0f};
    };
    auto compute = [&](int buf) {
        #pragma unroll
        for (int kt = 0; kt < 8; ++kt) {
            short8 bf[4];
            #pragma unroll
            for (int cg = 0; cg < 4; ++cg)
                bf[cg] = *(const short8*)(&Bs[buf][(cg * 8 + kt) * 512 + lane * 8]);
            #pragma unroll
            for (int cg = 0; cg < 4; ++cg)
                #pragma unroll
                for (int rg = 0; rg < 4; ++rg)
                    acc[rg][cg] = __builtin_amdgcn_mfma_f32_16x16x32_bf16(
                        a[rg][kt], bf[cg], acc[rg][cg], 0, 0, 0);
        }
    };
    auto fold = [&]() {
        #pragma unroll
        for (int rg = 0; rg < 4; ++rg)
            #pragma unroll
            for (int cg = 0; cg < 4; ++cg)
                #pragma unroll
                for (int r = 0; r < 4; ++r) {
                    float m = acc[rg][cg][r];
                    mn4[rg][r] = fminf(mn4[rg][r], m);
                    mx4[rg][r] = fmaxf(mx4[rg][r], m);
                }
    };

    // --- ct = 0, peeled: overlap A prologue with B0 staging + compute ---
    loadA(0);
    loadA(1);
    stageB(0, ybase);        // loads+writes; its vmcnt wait also covers A k0/k1
    __syncthreads();         // B0 visible to all waves
    stageB(1, ybase + 16384);  // ct=1 prefetch (done before compute, ~600 cyc)
    loadA(2); loadA(3); loadA(4); loadA(5); loadA(6); loadA(7);
    zeroAcc();
    compute(0);
    fold();
    ybase += 16384;

    // --- cts 1..7: steady state ---
    #pragma unroll 1
    for (int ct = 1; ct < 8; ++ct) {
        const int buf = ct & 1;
        zeroAcc();
        __syncthreads();  // lgkmcnt(0) drain: ct's B writes visible
        if (ct < 7)
            stageB(buf ^ 1, ybase + 16384);  // ct+1 prefetch, immediate
        compute(buf);
        fold();
        ybase += 16384;  // loop-carried: blocks cross-ct hoisting
    }

    // Single epilogue: quad-lane reduce, eval C twice (quasiconcavity),
    // fire-and-forget atomicMin (no read guard -- R3 post-mortem).
    #pragma unroll
    for (int rg = 0; rg < 4; ++rg) {
        #pragma unroll
        for (int r = 0; r < 4; ++r) {
            float mn = mn4[rg][r];
            float mx = mx4[rg][r];
            #pragma unroll
            for (int mofs = 1; mofs < 16; mofs <<= 1) {
                mn = fminf(mn, __shfl_xor(mn, mofs, 64));
                mx = fmaxf(mx, __shfl_xor(mx, mofs, 64));
            }
            if (lm == 0) {
                float cmin = fminf(c_of_m(mn), c_of_m(mx));
                int row = rowStart + w * 64 + rg * 16 + lq * 4 + r;
                atomicMinFloat(&out[row], cmin);
            }
        }
    }
}

extern "C" void kernel_launch(void* const* d_in, const int* in_sizes, int n_in,
                              void* d_out, int out_size, void* d_ws, size_t ws_size,
                              hipStream_t stream) {
    const float* Ex = (const float*)d_in[0];
    const float* Ey = (const float*)d_in[1];
    float* out = (float*)d_out;
    u16* Xs = (u16*)d_ws;                // 4 MB, panel layout
    u16* Ys = Xs + (size_t)NROWS * DIM;  // 4 MB, panel layout

    hipLaunchKernelGGL(normalize_kernel, dim3(NROWS / 4, 2), dim3(256), 0, stream,
                       Ex, Ey, Xs, Ys, out);
    hipLaunchKernelGGL(gemm_min_kernel, dim3(16 * 16), dim3(512), 0, stream,
                       Xs, Ys, out);
}